// Round 8
// baseline (490.960 us; speedup 1.0000x reference)
//
#include <hip/hip_runtime.h>
#include <hip/hip_bf16.h>

typedef __hip_bfloat16 bf16;

#define B_   8
#define C_   192
#define OC3  576
#define H_   128
#define W_   128
#define HW_  16384
#define HEADS_ 4
#define D_   48

typedef float f32x4 __attribute__((ext_vector_type(4)));
typedef __bf16 bf16x8 __attribute__((ext_vector_type(8)));
typedef __bf16 bf16x4 __attribute__((ext_vector_type(4)));

__device__ __forceinline__ float b2f(bf16 v) { return __bfloat162float(v); }

// packed 4-wide epilogue stores (p-contiguous)
__device__ __forceinline__ void stv4(bf16* p, const f32x4& v, float bi) {
    bf16x4 o;
#pragma unroll
    for (int r = 0; r < 4; ++r) o[r] = (__bf16)(v[r] + bi);
    *reinterpret_cast<bf16x4*>(p) = o;
}
__device__ __forceinline__ void stv4(float* p, const f32x4& v, float bi) {
    f32x4 o;
#pragma unroll
    for (int r = 0; r < 4; ++r) o[r] = v[r] + bi;
    *reinterpret_cast<f32x4*>(p) = o;
}

// async 16B global -> LDS (per-lane global addr; LDS dest = wave-uniform base + lane*16)
__device__ __forceinline__ void llds16(const void* g, void* l) {
    __builtin_amdgcn_global_load_lds(
        (const __attribute__((address_space(1))) unsigned int*)g,
        (__attribute__((address_space(3))) unsigned int*)l, 16, 0, 0);
}

// raw per-slot B staging registers (loads issued early; cvt/pack at write time)
template<typename TIn> struct BRaw;
template<> struct BRaw<float> {
    float v[8];
    __device__ __forceinline__ void load(const float* __restrict__ g) {
#pragma unroll
        for (int j = 0; j < 8; ++j) v[j] = g[(size_t)j * HW_];
    }
    __device__ __forceinline__ bf16x8 pack() const {
        bf16x8 o;
#pragma unroll
        for (int j = 0; j < 8; ++j) o[j] = (__bf16)v[j];
        return o;
    }
};
template<> struct BRaw<__bf16> {
    __bf16 v[8];
    __device__ __forceinline__ void load(const __bf16* __restrict__ g) {
#pragma unroll
        for (int j = 0; j < 8; ++j) v[j] = g[(size_t)j * HW_];
    }
    __device__ __forceinline__ bf16x8 pack() const {
        bf16x8 o;
#pragma unroll
        for (int j = 0; j < 8; ++j) o[j] = v[j];
        return o;
    }
};

// ---------------------------------------------------------------------------
// Convert qkv_w (576x192) fp32 -> bf16 (rows padded to 640; pad rows = finite
// poison, masked at GEMM store). grid 576 x 192 threads.
// ---------------------------------------------------------------------------
__global__ void cvt_w(const float* __restrict__ qkv_w, __bf16* __restrict__ Wq) {
    const int row = blockIdx.x, c = threadIdx.x;
    Wq[row * C_ + c] = (__bf16)qkv_w[row * C_ + c];
}

// ---------------------------------------------------------------------------
// MFMA GEMM, transpose-fused B: Y[b][o][p] = sum_k A[o][k]*X[b][k][p] + bias[o]
// B-operand is gathered DIRECTLY from the plane-major source (x fp32 for the
// qkv GEMM; bufB v-planes bf16 for the proj GEMM) — the tx_cvt / vtx
// transpose kernels are deleted. Per K-step each thread gathers 2 slots of
// 8 k-values at fixed p (each load instr = 4 x 64B coalesced segments),
// holds them in regs across the compute phase (T14 issue-early/write-late),
// then cvt+packs and ds_write_b128 to the swizzled LDS layout (linear slot
// order -> conflict-free writes). A stays global_load_lds, 3-buffer; B is
// 2-buffer. LDS 56 KB -> 2 blocks/CU. vmcnt(0) at the tail only drains loads
// issued one full compute phase earlier (L3-resident, ~200-300cy, covered).
// ---------------------------------------------------------------------------
template<typename TIn, typename TOut, int KK>
__global__ __launch_bounds__(512, 4) void mfma_gemm(
        const __bf16* __restrict__ Wp, const TIn* __restrict__ Xsrc,
        const float* __restrict__ bias, TOut* __restrict__ Y,
        const int O, const size_t a_bstride, const size_t x_bstride) {
    const int tid  = threadIdx.x;
    const int wid  = tid >> 6, lane = tid & 63;
    const int lm   = lane & 15, qd = lane >> 4;
    const int p0   = blockIdx.x * 256;
    const int o0   = blockIdx.y * 128;
    const int b    = blockIdx.z;
    const int wo0  = (wid >> 2) * 64;      // 2 o-rows of waves
    const int wn0  = (wid & 3) * 64;       // 4 p-cols of waves

    const __bf16* Wb = Wp + a_bstride * b + (size_t)o0 * KK;
    const TIn*    Xb = Xsrc + x_bstride * b + p0;    // row stride HW_ (k-major planes)

    // [buf][row(p or o)][slot][8] bf16; chunk (row,slot) holds global
    // k8 = slot ^ ((row>>1)&3)  (both-sides XOR swizzle, read side matches).
    __shared__ __bf16 As[3][4096];    // 128 o x 32k   (8 KB/buf)
    __shared__ __bf16 Bs[2][8192];    // 256 p x 32k   (16 KB/buf)

    f32x4 acc[4][4] = {};
    BRaw<TIn> rb[2];

    // per-thread B gather geometry (slot = p*4 + cslot, linear -> conflict-free writes)
    const int s0o = tid,       p_0 = s0o >> 2, cs0 = s0o & 3;
    const int s1o = 512 + tid, p_1 = s1o >> 2, cs1 = s1o & 3;
    const int k80 = cs0 ^ ((p_0 >> 1) & 3);
    const int k81 = cs1 ^ ((p_1 >> 1) & 3);

    auto ldB = [&](int t) {
        const int k0 = t * 32;
        rb[0].load(Xb + (size_t)(k0 + k80 * 8) * HW_ + p_0);
        rb[1].load(Xb + (size_t)(k0 + k81 * 8) * HW_ + p_1);
    };
    auto wrB = [&](int buf) {
        *(bf16x8*)&Bs[buf][(size_t)s0o * 8] = rb[0].pack();
        *(bf16x8*)&Bs[buf][(size_t)s1o * 8] = rb[1].pack();
    };
    auto ldA = [&](int buf, int t) {
        const int k0 = t * 32;
        const int row = tid >> 2, cslot = tid & 3;
        const int k8  = cslot ^ ((row >> 1) & 3);
        llds16(Wb + (size_t)row * KK + k0 + k8 * 8,
               &As[buf][(size_t)(wid * 64) * 8]);
    };

    constexpr int NT = KK >> 5;     // 6

    // prologue: tile 0 loaded+published; tile 1 issued (in flight)
    ldB(0); ldA(0, 0);
    asm volatile("s_waitcnt vmcnt(0)" ::: "memory");
    wrB(0);
    ldB(1); ldA(1, 1);
    asm volatile("s_waitcnt lgkmcnt(0)" ::: "memory");
    __builtin_amdgcn_s_barrier();
    __builtin_amdgcn_sched_barrier(0);

    const int csl = qd ^ ((lm >> 1) & 3);  // swizzled chunk slot for ds_read

#pragma unroll
    for (int t = 0; t < NT; ++t) {
        const int cur2 = t & 1;                      // static after unroll
        bf16x8 af[4], bfr[4];
#pragma unroll
        for (int i = 0; i < 4; ++i)
            af[i] = *(const bf16x8*)&As[t % 3][((wo0 + i * 16 + lm) * 4 + csl) * 8];
#pragma unroll
        for (int j = 0; j < 4; ++j)
            bfr[j] = *(const bf16x8*)&Bs[cur2][((wn0 + j * 16 + lm) * 4 + csl) * 8];
#pragma unroll
        for (int i = 0; i < 4; ++i)
#pragma unroll
            for (int j = 0; j < 4; ++j)
                // swapped: X-frag is the A operand -> D reg index runs along p
                acc[i][j] = __builtin_amdgcn_mfma_f32_16x16x32_bf16(
                    bfr[j], af[i], acc[i][j], 0, 0, 0);

        if (t + 1 < NT) {
            __builtin_amdgcn_sched_barrier(0);
            asm volatile("s_waitcnt vmcnt(0)" ::: "memory");  // tile t+1 arrived
            wrB(cur2 ^ 1);                                    // publish B(t+1)
            if (t + 2 < NT) { ldB(t + 2); ldA((t + 2) % 3, t + 2); }
            asm volatile("s_waitcnt lgkmcnt(0)" ::: "memory");
            __builtin_amdgcn_s_barrier();
            __builtin_amdgcn_sched_barrier(0);
        }
    }

    // epilogue: acc[i][j][r] = Y[o0+wo0+i*16+lm][p0+wn0+j*16+qd*4+r]
    TOut* Yb = Y + (size_t)b * O * HW_;
#pragma unroll
    for (int i = 0; i < 4; ++i) {
        const int o = o0 + wo0 + i * 16 + lm;
        if (o < O) {
            const float bi = bias[o];
#pragma unroll
            for (int j = 0; j < 4; ++j) {
                const int p = p0 + wn0 + j * 16 + qd * 4;
                stv4(&Yb[(size_t)o * HW_ + p], acc[i][j], bi);
            }
        }
    }
}

// ---------------------------------------------------------------------------
// depthwise 3x3 + fused sum-of-squares (for q,k L2 norms).
// grid (ch=576, b=8), block 256. Whole 128x128 plane staged in LDS (32 KB).
// Statically-rotated rows[3] window; sumsq reduction skipped for v channels.
// ---------------------------------------------------------------------------
__device__ __forceinline__ void dw_load_row(const __bf16* plane, int yy, int x0,
                                            float* r) {
    if (yy < 0 || yy > 127) {
#pragma unroll
        for (int i = 0; i < 10; ++i) r[i] = 0.f;
        return;
    }
    const __bf16* row = plane + yy * 128;
    bf16x8 v = *(const bf16x8*)(row + x0);
    r[0] = (x0 > 0) ? (float)row[x0 - 1] : 0.f;
#pragma unroll
    for (int i = 0; i < 8; ++i) r[1 + i] = (float)v[i];
    r[9] = (x0 + 8 < 128) ? (float)row[x0 + 8] : 0.f;
}

__global__ __launch_bounds__(256) void dwconv_fused(
        const bf16* __restrict__ in, const float* __restrict__ w9,
        const float* __restrict__ bias, bf16* __restrict__ out,
        float* __restrict__ sumsq) {
    const int ch = blockIdx.x;
    const int b  = blockIdx.y;
    const int tid = threadIdx.x;
    const char* ib = (const char*)(in + ((size_t)b * OC3 + ch) * HW_);

    __shared__ __bf16 plane[16384];
    __shared__ float red[256];

    {
        const int wid = tid >> 6, lane = tid & 63;
        char* lbase = (char*)plane + wid * 8192;
        const char* gbase = ib + wid * 8192;
#pragma unroll
        for (int i = 0; i < 8; ++i)
            llds16(gbase + i * 1024 + lane * 16, lbase + i * 1024);
    }

    float wv[9];
#pragma unroll
    for (int i = 0; i < 9; ++i) wv[i] = w9[ch * 9 + i];
    const float bi = bias[ch];

    __syncthreads();

    const int x0 = (tid & 15) * 8;
    const int y0 = (tid >> 4) * 8;
    bf16* ob = out + ((size_t)b * OC3 + ch) * HW_;

    float rows[3][10];
    dw_load_row(plane, y0 - 1, x0, rows[0]);
    dw_load_row(plane, y0,     x0, rows[1]);

    float ss = 0.f;
#pragma unroll
    for (int yi = 0; yi < 8; ++yi) {
        float* r0 = rows[yi % 3];            // constexpr after full unroll
        float* r1 = rows[(yi + 1) % 3];
        float* r2 = rows[(yi + 2) % 3];
        dw_load_row(plane, y0 + yi + 1, x0, r2);
        bf16x8 st;
#pragma unroll
        for (int xx = 0; xx < 8; ++xx) {
            float o = bi;
#pragma unroll
            for (int dx = 0; dx < 3; ++dx) {
                o += wv[0 + dx] * r0[xx + dx];
                o += wv[3 + dx] * r1[xx + dx];
                o += wv[6 + dx] * r2[xx + dx];
            }
            ss += o * o;
            st[xx] = (__bf16)o;
        }
        *(bf16x8*)(ob + (y0 + yi) * 128 + x0) = st;
    }

    if (ch < 384) {               // block-uniform: only q,k channels need norms
        red[tid] = ss;
        __syncthreads();
        for (int stx = 128; stx > 0; stx >>= 1) {
            if (tid < stx) red[tid] += red[tid + stx];
            __syncthreads();
        }
        if (tid == 0) sumsq[b * OC3 + ch] = red[0];
    }
}

// ---------------------------------------------------------------------------
// MFMA QK^T partials: S_part[slice][i][j] = sum_{n in 512-slice} q[i,n]*k[j,n]
// grid (32, HEADS, B), 256 thr. LDS: q/k chunks 48x128, rows padded to 136
// (row stride 17*16B => 2-way max bank aliasing on ds_read_b128). 4 waves
// split each 128-chunk into K=32 pieces; fp32 cross-wave reduce in LDS.
// ---------------------------------------------------------------------------
__global__ __launch_bounds__(256) void qk_mfma(const bf16* __restrict__ qkv2,
                                               float* __restrict__ Spart) {
    const int slice = blockIdx.x, h = blockIdx.y, b = blockIdx.z;
    const __bf16* qb = (const __bf16*)(qkv2 + ((size_t)b * OC3 + h * D_) * HW_);
    const __bf16* kb = (const __bf16*)(qkv2 + ((size_t)b * OC3 + 192 + h * D_) * HW_);

    __shared__ char smem[36864];                 // max(staging 26112, reduce 36864)
    __bf16* qs = (__bf16*)smem;                  // 48 x 136
    __bf16* ks = (__bf16*)(smem + 13056);        // 48 x 136
    float*  red = (float*)smem;                  // 4 x 2304

    const int tid = threadIdx.x, wid = tid >> 6, lane = tid & 63;
    const int lm = lane & 15, qd = lane >> 4;
    const int kw0 = wid * 32;

    f32x4 acc[3][3] = {};

    for (int sub = 0; sub < 4; ++sub) {
        const int n0 = slice * 512 + sub * 128;
        __syncthreads();
        for (int t = tid; t < 768; t += 256) {
            int r = t >> 4, c8 = t & 15;
            *(bf16x8*)&qs[r * 136 + c8 * 8] =
                *(const bf16x8*)(qb + (size_t)r * HW_ + n0 + c8 * 8);
            *(bf16x8*)&ks[r * 136 + c8 * 8] =
                *(const bf16x8*)(kb + (size_t)r * HW_ + n0 + c8 * 8);
        }
        __syncthreads();

        bf16x8 af[3], bfr[3];
#pragma unroll
        for (int i = 0; i < 3; ++i)
            af[i] = *(const bf16x8*)&qs[(i * 16 + lm) * 136 + kw0 + qd * 8];
#pragma unroll
        for (int j = 0; j < 3; ++j)
            bfr[j] = *(const bf16x8*)&ks[(j * 16 + lm) * 136 + kw0 + qd * 8];
#pragma unroll
        for (int i = 0; i < 3; ++i)
#pragma unroll
            for (int j = 0; j < 3; ++j)
                acc[i][j] = __builtin_amdgcn_mfma_f32_16x16x32_bf16(
                    af[i], bfr[j], acc[i][j], 0, 0, 0);
    }

    __syncthreads();
    float* wb = red + wid * 2304;
#pragma unroll
    for (int i = 0; i < 3; ++i)
#pragma unroll
        for (int j = 0; j < 3; ++j)
#pragma unroll
            for (int r = 0; r < 4; ++r)
                wb[(i * 16 + qd * 4 + r) * 48 + j * 16 + lm] = acc[i][j][r];
    __syncthreads();

    float* outp = Spart + ((size_t)((b * HEADS_ + h) * 32 + slice)) * 2304;
    for (int t = tid; t < 2304; t += 256)
        outp[t] = red[t] + red[2304 + t] + red[4608 + t] + red[6912 + t];
}

// ---------------------------------------------------------------------------
// Parallel 32-slice reduction: Sred[bh][t] = sum_sl Spart[bh][sl][t].
// grid (9, 32bh) x 256 thr = one thread per output element; coalesced loads.
// ---------------------------------------------------------------------------
__global__ void sreduce(const float* __restrict__ Spart, float* __restrict__ Sred) {
    const int bh = blockIdx.y;
    const int t  = blockIdx.x * 256 + threadIdx.x;   // 9*256 = 2304 exactly
    const float* Sp = Spart + (size_t)bh * 32 * 2304;
    float v = 0.f;
#pragma unroll
    for (int sl = 0; sl < 32; ++sl) v += Sp[sl * 2304 + t];
    Sred[(size_t)bh * 2304 + t] = v;
}

// ---------------------------------------------------------------------------
// apply norms (from fused sumsq) + temperature, softmax over pre-reduced S.
// ---------------------------------------------------------------------------
__global__ void softmax48(const float* __restrict__ Sred, const float* __restrict__ sumsq,
                          const float* __restrict__ temp, float* __restrict__ A) {
    const int h = blockIdx.x, b = blockIdx.y;
    const int i = threadIdx.x;
    if (i >= 48) return;
    const float* sq = sumsq + b * OC3 + h * D_;
    const float* sk = sumsq + b * OC3 + 192 + h * D_;
    const float t = temp[h];
    const float* Sp = Sred + (size_t)(b * HEADS_ + h) * 2304;

    const float rqi = 1.0f / fmaxf(sqrtf(sq[i]), 1e-12f);

    float s[48];
#pragma unroll
    for (int j = 0; j < 48; ++j)
        s[j] = Sp[i * 48 + j] * rqi * (1.0f / fmaxf(sqrtf(sk[j]), 1e-12f)) * t;
    float m = -1e30f;
#pragma unroll
    for (int j = 0; j < 48; ++j) m = fmaxf(m, s[j]);
    float sum = 0.f;
#pragma unroll
    for (int j = 0; j < 48; ++j) { s[j] = expf(s[j] - m); sum += s[j]; }
    float inv = 1.0f / sum;
    float* Ao = A + ((size_t)(b * HEADS_ + h) * 48 + i) * 48;
#pragma unroll
    for (int j = 0; j < 48; ++j) Ao[j] = s[j] * inv;
}

// ---------------------------------------------------------------------------
// Wf[b][o][c'] = sum_i proj_w[o][h*48+i] * A[b,h][i][j]   (c' = h*48+j)
// ---------------------------------------------------------------------------
__global__ void wfuse(const float* __restrict__ proj_w, const float* __restrict__ A,
                      __bf16* __restrict__ Wf) {
    const int o = blockIdx.x, b = blockIdx.y;
    const int cp = threadIdx.x;
    const int h = cp / 48, j = cp % 48;
    const float* wrow = proj_w + o * C_ + h * D_;
    const float* Ah = A + (size_t)(b * HEADS_ + h) * 2304;
    float s = 0.f;
#pragma unroll
    for (int i = 0; i < 48; ++i) s += wrow[i] * Ah[i * 48 + j];
    Wf[((size_t)b * 256 + o) * C_ + cp] = (__bf16)s;
}

// ---------------------------------------------------------------------------
extern "C" void kernel_launch(void* const* d_in, const int* in_sizes, int n_in,
                              void* d_out, int out_size, void* d_ws, size_t ws_size,
                              hipStream_t stream) {
    const float* x      = (const float*)d_in[0];
    const float* qkv_w  = (const float*)d_in[1];
    const float* qkv_b  = (const float*)d_in[2];
    const float* dw_w   = (const float*)d_in[3];
    const float* dw_b   = (const float*)d_in[4];
    const float* temp   = (const float*)d_in[5];
    const float* proj_w = (const float*)d_in[6];
    const float* proj_b = (const float*)d_in[7];
    float* out = (float*)d_out;

    char* ws = (char*)d_ws;
    const size_t WQ_BYTES  = 640 * C_ * 2;                   // 245,760 (padded)
    const size_t WF_BYTES  = (size_t)B_ * 256 * C_ * 2;      // 786,432 (padded)
    const size_t QKV_BYTES = (size_t)B_ * OC3 * HW_ * 2;     // 150,994,944

    size_t off = 0;
    __bf16* Wq    = (__bf16*)(ws + off); off += WQ_BYTES;
    __bf16* Wf    = (__bf16*)(ws + off); off += WF_BYTES;
    bf16*   bufA  = (bf16*)(ws + off);   off += QKV_BYTES;   // qkv after 1x1
    bf16*   bufB  = (bf16*)(ws + off);   off += QKV_BYTES;   // qkv after dwconv
    float*  sumsq = (float*)(ws + off);  off += OC3 * B_ * 4;
    float*  Spart = (float*)(ws + off);  off += (size_t)32 * 2304 * 4 * 32; // 9.4 MB
    float*  Sred  = (float*)(ws + off);  off += (size_t)32 * 2304 * 4;      // 294 KB
    float*  Attn  = (float*)(ws + off);  off += 294912;

    cvt_w<<<dim3(OC3), 192, 0, stream>>>(qkv_w, Wq);

    // qkv 1x1: B gathered directly from x (fp32, plane-major) — no tx_cvt.
    mfma_gemm<float, bf16, C_><<<dim3(HW_ / 256, 5, B_), 512, 0, stream>>>(
        Wq, x, qkv_b, bufA, OC3, 0, (size_t)C_ * HW_);

    dwconv_fused<<<dim3(OC3, B_), 256, 0, stream>>>(bufA, dw_w, dw_b, bufB, sumsq);

    qk_mfma<<<dim3(32, HEADS_, B_), 256, 0, stream>>>(bufB, Spart);

    sreduce<<<dim3(9, 32), 256, 0, stream>>>(Spart, Sred);

    softmax48<<<dim3(HEADS_, B_), 64, 0, stream>>>(Sred, sumsq, temp, Attn);

    wfuse<<<dim3(C_, B_), 192, 0, stream>>>(proj_w, Attn, Wf);

    // proj 1x1: B gathered directly from bufB v-planes (bf16) — no vtx.
    mfma_gemm<__bf16, float, C_><<<dim3(HW_ / 256, 2, B_), 512, 0, stream>>>(
        Wf, (const __bf16*)bufB + (size_t)384 * HW_, proj_b, out, C_,
        (size_t)256 * C_, (size_t)OC3 * HW_);
}